// Round 2
// baseline (635.076 us; speedup 1.0000x reference)
//
#include <hip/hip_runtime.h>
#include <hip/hip_bf16.h>

// Problem constants
#define B_SZ   16384
#define DIN    2048
#define H1_SZ  512
#define H2_SZ  128
#define N_EXP  8
#define N_CLS  10
#define N1     4608   // 8*512 experts + 512 gate
#define N2     1152   // 8*128 experts + 128 gate

typedef __attribute__((ext_vector_type(8))) __bf16 bf16x8;
typedef __attribute__((ext_vector_type(4))) float  floatx4;
typedef __attribute__((ext_vector_type(4))) short  short4v;
typedef __attribute__((ext_vector_type(8))) short  short8v;

__device__ __forceinline__ float bf2f(short s) {
  unsigned int u = ((unsigned int)(unsigned short)s) << 16;
  float f; __builtin_memcpy(&f, &u, 4); return f;
}

// ---------------------------------------------------------------------------
// Prep 1: features = concat(fs, fp) -> bf16 X[B][DIN]
// ---------------------------------------------------------------------------
__global__ void convert_features_kernel(const float* __restrict__ fs,
                                        const float* __restrict__ fp,
                                        __hip_bfloat16* __restrict__ X) {
  const int nf4 = B_SZ * (DIN / 4);          // 8,388,608 float4 chunks
  const float4* fs4 = (const float4*)fs;
  const float4* fp4 = (const float4*)fp;
  for (int i = blockIdx.x * blockDim.x + threadIdx.x; i < nf4;
       i += gridDim.x * blockDim.x) {
    int c = i & 511;                         // DIN/4 = 512 chunks per row
    int row = i >> 9;
    float4 v = (c < 256) ? fs4[(size_t)row * 256 + c]
                         : fp4[(size_t)row * 256 + (c - 256)];
    union { short4v v4; __hip_bfloat16 h[4]; } u;
    u.h[0] = __float2bfloat16(v.x);
    u.h[1] = __float2bfloat16(v.y);
    u.h[2] = __float2bfloat16(v.z);
    u.h[3] = __float2bfloat16(v.w);
    *(short4v*)(X + (size_t)i * 4) = u.v4;
  }
}

// ---------------------------------------------------------------------------
// Prep 2: transpose-convert weights to B^T layout (rows = n, stride K), bf16.
// ---------------------------------------------------------------------------
__global__ void transpose_convert_kernel(const float* __restrict__ expert_src,
                                         const float* __restrict__ gate_src,
                                         int K, int H, int E,
                                         __hip_bfloat16* __restrict__ out) {
  __shared__ float t[32][33];
  int k0 = blockIdx.x * 32;
  int n0 = blockIdx.y * 32;   // 32 | H, so a tile never straddles experts
  int e = n0 / H;
  const float* src; int h0;
  if (e < E) { src = expert_src + (size_t)e * K * H; h0 = n0 - e * H; }
  else       { src = gate_src;                       h0 = n0 - E * H; }
  int tx = threadIdx.x, ty = threadIdx.y;
  #pragma unroll
  for (int j = 0; j < 4; ++j) {
    int r = ty + j * 8;
    t[r][tx] = src[(size_t)(k0 + r) * H + h0 + tx];
  }
  __syncthreads();
  #pragma unroll
  for (int j = 0; j < 4; ++j) {
    int r = ty + j * 8;
    out[(size_t)(n0 + r) * K + k0 + tx] = __float2bfloat16(t[tx][r]);
  }
}

// ---------------------------------------------------------------------------
// gemm1: 256x256-tile, 8-wave (2Mx4N), 8-phase schedule, counted vmcnt.
//
// LDS: 8 sub-tiles of [256 rows][32 k] bf16 (16 KB each, 128 KB total):
//   sub = buf*4 + mat*2 + ks   (buf: K-tile parity; mat: 0=A,1=B; ks: K-half)
// Swizzle: within a row (64 B = 4 chunks of 16 B), stored slot cs holds
// logical chunk cs ^ ((row>>1)&3). global_load_lds dest stays linear (HW
// constraint); only the per-lane GLOBAL source address is permuted (within an
// aligned 64 B segment, so coalescing is preserved). Fragment ds_read_b128
// then covers a contiguous 1 KB stripe per fragment = perfectly bank-balanced
// (same class as the R0-verified swizzle: SQ_LDS_BANK_CONFLICT == 0).
//
// Phase structure (the publish ordering is the correctness-critical part):
//   { ds_read frags ; issue 1 stage_sub ; s_waitcnt vmcnt(8) ; s_barrier ;
//     s_waitcnt lgkmcnt(0) + sched_barrier ; setprio(1) 16xMFMA setprio(0) ;
//     sched_barrier ; s_barrier }
// Invariants (verified by hand over the stage queue):
//  * PUBLISH: every phase issues exactly 1 stage_sub (2 loads) and its
//    vmcnt(8) completes exactly the oldest one; a tile staged at phase p is
//    completed-by-vmcnt at phase p+4 and first ds_read at phase p+5 or p+6 —
//    i.e. always >= 1 full vmcnt+barrier AFTER the covering wait, for every
//    wave. (This fixes R1's race where the covering vmcnt was in the same
//    phase as the read.)
//  * WAR: the explicit lgkmcnt(0) between the two barriers means all waves'
//    ds_reads are complete before anyone passes barrier2; restaging of that
//    region is issued only after barrier2. Safe.
//  * T4: the load queue is never drained to 0 in the main loop (raw
//    s_barrier, never __syncthreads).
// ---------------------------------------------------------------------------
__device__ __forceinline__ void stage_sub(
    const __hip_bfloat16* __restrict__ src, int ld, int row0, int kofs,
    __hip_bfloat16* dst, int tid) {
  #pragma unroll
  for (int j = 0; j < 2; ++j) {
    int c = j * 512 + tid;                 // chunk 0..1023 (16 B each)
    int r = c >> 2;                        // row 0..255
    int cl = (c & 3) ^ ((r >> 1) & 3);     // logical k-chunk for this slot
    __builtin_amdgcn_global_load_lds(
        (const __attribute__((address_space(1))) unsigned int*)(
            src + (size_t)(row0 + r) * ld + kofs + cl * 8),
        (__attribute__((address_space(3))) unsigned int*)(dst + c * 8),
        16, 0, 0);
  }
}

__device__ __forceinline__ bf16x8 ldsfrag(const __hip_bfloat16* sub, int r, int lquad) {
  int slot = lquad ^ ((r >> 1) & 3);
  return *(const bf16x8*)(sub + r * 32 + slot * 8);
}

template <bool RDB, int MH>
__device__ __forceinline__ void phase8(
    const __hip_bfloat16* Asub, const __hip_bfloat16* Bsub,
    floatx4 (&acc)[8][4], bf16x8 (&b)[4],
    int wm, int wn, int lrow, int lquad,
    const __hip_bfloat16* __restrict__ ssrc, int sld, int srow0, int skofs,
    __hip_bfloat16* sdst, int tid) {
  bf16x8 a[4];
  #pragma unroll
  for (int q = 0; q < 4; ++q)
    a[q] = ldsfrag(Asub, wm + (MH * 4 + q) * 16 + lrow, lquad);
  if (RDB) {
    #pragma unroll
    for (int nt = 0; nt < 4; ++nt)
      b[nt] = ldsfrag(Bsub, wn + nt * 16 + lrow, lquad);
  }
  stage_sub(ssrc, sld, srow0, skofs, sdst, tid);
  asm volatile("s_waitcnt vmcnt(8)" ::: "memory");   // publish-for-NEXT-phase
  __builtin_amdgcn_s_barrier();
  asm volatile("s_waitcnt lgkmcnt(0)" ::: "memory"); // frags in regs (WAR key)
  __builtin_amdgcn_sched_barrier(0);                 // rule #18: pin MFMAs below
  __builtin_amdgcn_s_setprio(1);
  #pragma unroll
  for (int q = 0; q < 4; ++q)
    #pragma unroll
    for (int nt = 0; nt < 4; ++nt)
      acc[MH * 4 + q][nt] = __builtin_amdgcn_mfma_f32_16x16x32_bf16(
          a[q], b[nt], acc[MH * 4 + q][nt], 0, 0, 0);
  __builtin_amdgcn_s_setprio(0);
  __builtin_amdgcn_sched_barrier(0);                 // keep MFMAs above bar2
  __builtin_amdgcn_s_barrier();
  __builtin_amdgcn_sched_barrier(0);                 // pin phase boundary
}

__global__ __launch_bounds__(512, 2) void gemm1_kernel8(
    const __hip_bfloat16* __restrict__ X, const __hip_bfloat16* __restrict__ W1T,
    const float* __restrict__ eb1, const float* __restrict__ gb1,
    __hip_bfloat16* __restrict__ H1) {
  __shared__ __align__(16) __hip_bfloat16 lds[8][256 * 32];

  const int tid  = threadIdx.x;
  const int lane = tid & 63;
  const int wave = tid >> 6;
  const int wm   = (wave >> 2) * 128;    // 0 or 128
  const int wn   = (wave & 3) * 64;      // 0,64,128,192
  const int lrow  = lane & 15;
  const int lquad = lane >> 4;

  // bijective XCD swizzle (1152 % 8 == 0): each XCD gets a contiguous run of
  // tiles -> A/B panels stay hot in that XCD's L2.
  int flat = blockIdx.x;
  int swz  = (flat & 7) * ((int)gridDim.x >> 3) + (flat >> 3);
  int m0 = (swz / (N1 / 256)) * 256;
  int n0 = (swz % (N1 / 256)) * 256;

  floatx4 acc[8][4] = {};
  bf16x8 b[4];

  const int KT = DIN / 64;   // 32 K-tiles

  // prologue: tile0 (4 subs) + tile1 ks0 (2 subs) = 12 loads in flight.
  // Queue order: lds[0], lds[2], lds[1], lds[3], lds[4], lds[6].
  stage_sub(X,   DIN, m0, 0,  lds[0], tid);  // A buf0 ks0  <- tile0
  stage_sub(W1T, DIN, n0, 0,  lds[2], tid);  // B buf0 ks0
  stage_sub(X,   DIN, m0, 32, lds[1], tid);  // A buf0 ks1
  stage_sub(W1T, DIN, n0, 32, lds[3], tid);  // B buf0 ks1
  stage_sub(X,   DIN, m0, 64, lds[4], tid);  // A buf1 ks0  <- tile1
  stage_sub(W1T, DIN, n0, 64, lds[6], tid);  // B buf1 ks0
  asm volatile("s_waitcnt vmcnt(8)" ::: "memory");  // completes lds[0], lds[2]
  __builtin_amdgcn_s_barrier();
  __builtin_amdgcn_sched_barrier(0);

  for (int i = 0; i < KT / 2; ++i) {
    int T  = 2 * i;
    int k1 = (T + 1) * 64;                     // tile T+1 (always valid)
    int k2 = min(T + 2, KT - 1) * 64;          // tile T+2 (clamped; the
    int k3 = min(T + 3, KT - 1) * 64;          //  clamped stages are never read)
    phase8<true,  0>(lds[0], lds[2], acc, b, wm, wn, lrow, lquad,
                     X,   DIN, m0, k1 + 32, lds[5], tid);   // ph1
    phase8<false, 1>(lds[0], lds[2], acc, b, wm, wn, lrow, lquad,
                     W1T, DIN, n0, k1 + 32, lds[7], tid);   // ph2
    phase8<true,  0>(lds[1], lds[3], acc, b, wm, wn, lrow, lquad,
                     X,   DIN, m0, k2,      lds[0], tid);   // ph3
    phase8<false, 1>(lds[1], lds[3], acc, b, wm, wn, lrow, lquad,
                     W1T, DIN, n0, k2,      lds[2], tid);   // ph4
    phase8<true,  0>(lds[4], lds[6], acc, b, wm, wn, lrow, lquad,
                     X,   DIN, m0, k2 + 32, lds[1], tid);   // ph5
    phase8<false, 1>(lds[4], lds[6], acc, b, wm, wn, lrow, lquad,
                     W1T, DIN, n0, k2 + 32, lds[3], tid);   // ph6
    phase8<true,  0>(lds[5], lds[7], acc, b, wm, wn, lrow, lquad,
                     X,   DIN, m0, k3,      lds[4], tid);   // ph7
    phase8<false, 1>(lds[5], lds[7], acc, b, wm, wn, lrow, lquad,
                     W1T, DIN, n0, k3,      lds[6], tid);   // ph8
  }

  // epilogue: bias + relu -> bf16. C/D layout: col = lane&15, row = quad*4+r.
  // n0 is a multiple of 256; expert/gate bias boundary at 4096 = 16*256, so a
  // block never straddles it.
  const float* bias = (n0 < N_EXP * H1_SZ) ? (eb1 + n0) : (gb1 + (n0 - N_EXP * H1_SZ));
  #pragma unroll
  for (int nt = 0; nt < 4; ++nt) {
    int col = wn + nt * 16 + lrow;
    float bv = bias[col];
    #pragma unroll
    for (int mt = 0; mt < 8; ++mt) {
      #pragma unroll
      for (int r = 0; r < 4; ++r) {
        int row = m0 + wm + mt * 16 + lquad * 4 + r;
        float v = acc[mt][nt][r] + bv;
        v = v > 0.f ? v : 0.f;
        H1[(size_t)row * N1 + n0 + col] = __float2bfloat16(v);
      }
    }
  }
}

// ---------------------------------------------------------------------------
// 128x128 MFMA GEMM core (kept for gemm2, whose N-slice is only 128 wide).
// ---------------------------------------------------------------------------
__device__ __forceinline__ void gemm_core(
    const __hip_bfloat16* __restrict__ A,  int lda,
    const __hip_bfloat16* __restrict__ BT, int K,
    const float* __restrict__ bias,
    __hip_bfloat16* __restrict__ O, int ldo) {
  __shared__ __align__(16) __hip_bfloat16 As[128 * 64];
  __shared__ __align__(16) __hip_bfloat16 Bs[128 * 64];

  const int tid  = threadIdx.x;
  const int lane = tid & 63;
  const int wave = tid >> 6;
  const int wm   = (wave >> 1) * 64;
  const int wn   = (wave & 1) * 64;
  const int lrow  = lane & 15;
  const int lquad = lane >> 4;

  floatx4 acc[4][4] = {};

  for (int k0 = 0; k0 < K; k0 += 64) {
    #pragma unroll
    for (int j = 0; j < 4; ++j) {
      int chunk = j * 256 + tid;       // 0..1023 chunks of 8 bf16 (16 B)
      int mi = chunk >> 3;             // tile row 0..127
      int cs = chunk & 7;              // stored chunk slot 0..7
      int cl = cs ^ (mi & 7);          // logical k-chunk held in this slot
      __builtin_amdgcn_global_load_lds(
          (const __attribute__((address_space(1))) unsigned int*)(A + (size_t)mi * lda + k0 + cl * 8),
          (__attribute__((address_space(3))) unsigned int*)(As + chunk * 8),
          16, 0, 0);
      __builtin_amdgcn_global_load_lds(
          (const __attribute__((address_space(1))) unsigned int*)(BT + (size_t)mi * K + k0 + cl * 8),
          (__attribute__((address_space(3))) unsigned int*)(Bs + chunk * 8),
          16, 0, 0);
    }
    __syncthreads();
    #pragma unroll
    for (int ks = 0; ks < 2; ++ks) {
      bf16x8 a[4], b[4];
      #pragma unroll
      for (int t = 0; t < 4; ++t) {
        int ar = wm + t * 16 + lrow;
        int br = wn + t * 16 + lrow;
        int ca = (ks * 4 + lquad) ^ (ar & 7);   // swizzled chunk slot
        int cb = (ks * 4 + lquad) ^ (br & 7);
        a[t] = *(const bf16x8*)(As + ar * 64 + ca * 8);
        b[t] = *(const bf16x8*)(Bs + br * 64 + cb * 8);
      }
      #pragma unroll
      for (int mt = 0; mt < 4; ++mt)
        #pragma unroll
        for (int nt = 0; nt < 4; ++nt)
          acc[mt][nt] = __builtin_amdgcn_mfma_f32_16x16x32_bf16(
              a[mt], b[nt], acc[mt][nt], 0, 0, 0);
    }
    __syncthreads();
  }

  #pragma unroll
  for (int nt = 0; nt < 4; ++nt) {
    int col = wn + nt * 16 + lrow;
    float bv = bias[col];
    #pragma unroll
    for (int mt = 0; mt < 4; ++mt) {
      #pragma unroll
      for (int r = 0; r < 4; ++r) {
        int row = wm + mt * 16 + lquad * 4 + r;
        float v = acc[mt][nt][r] + bv;
        v = v > 0.f ? v : 0.f;
        O[(size_t)row * ldo + col] = __float2bfloat16(v);
      }
    }
  }
}

// Layer 2: per z in 0..8: H1 block [B][512] @ W2T[z]^T -> relu -> H2 block [B][128]
__global__ __launch_bounds__(256, 2) void gemm2_kernel(
    const __hip_bfloat16* __restrict__ H1, const __hip_bfloat16* __restrict__ W2T,
    const float* __restrict__ eb2, const float* __restrict__ gb2,
    __hip_bfloat16* __restrict__ H2) {
  int m0 = blockIdx.y * 128;
  int z  = blockIdx.z;                 // 0..7 experts, 8 = gate
  const float* bias = (z < N_EXP) ? (eb2 + z * H2_SZ) : gb2;
  gemm_core(H1 + (size_t)m0 * N1 + z * H1_SZ, N1,
            W2T + (size_t)z * H2_SZ * H1_SZ, H1_SZ,
            bias,
            H2 + (size_t)m0 * N2 + z * H2_SZ, N2);
}

// ---------------------------------------------------------------------------
// Layer 3 fused: gate logits + softmax, expert logits + log_softmax, weighted
// sum. 8 threads per batch row (thread j = expert j and gate col j).
// ---------------------------------------------------------------------------
__global__ __launch_bounds__(256) void layer3_kernel(
    const __hip_bfloat16* __restrict__ H2,
    const float* __restrict__ gW3, const float* __restrict__ gb3,
    const float* __restrict__ eW3, const float* __restrict__ eb3,
    float* __restrict__ out, float* __restrict__ gate_out) {
  int tid  = threadIdx.x;
  int j    = tid & 7;
  int rloc = tid >> 3;                             // 0..31
  long row = (long)blockIdx.x * 32 + rloc;
  const __hip_bfloat16* hrow = H2 + row * N2;

  float accg = 0.f;
  float acc[N_CLS];
  #pragma unroll
  for (int c = 0; c < N_CLS; ++c) acc[c] = 0.f;

  #pragma unroll 4
  for (int k8 = 0; k8 < 16; ++k8) {
    short8v hg8 = *(const short8v*)(hrow + N_EXP * H2_SZ + k8 * 8);  // gate block
    short8v he8 = *(const short8v*)(hrow + j * H2_SZ + k8 * 8);      // expert j
    #pragma unroll
    for (int t = 0; t < 8; ++t) {
      int k = k8 * 8 + t;
      float hg = bf2f(hg8[t]);
      float he = bf2f(he8[t]);
      accg += hg * gW3[k * N_EXP + j];
      const float* w = eW3 + (size_t)(j * H2_SZ + k) * N_CLS;
      #pragma unroll
      for (int c = 0; c < N_CLS; ++c) acc[c] += he * w[c];
    }
  }

  // gate softmax across the 8 threads of this row
  float gj = accg + gb3[j];
  float mx = gj;
  mx = fmaxf(mx, __shfl_xor(mx, 1));
  mx = fmaxf(mx, __shfl_xor(mx, 2));
  mx = fmaxf(mx, __shfl_xor(mx, 4));
  float ex = __expf(gj - mx);
  float s = ex;
  s += __shfl_xor(s, 1);
  s += __shfl_xor(s, 2);
  s += __shfl_xor(s, 4);
  float gp = ex / s;

  // expert-local log_softmax over 10 classes
  float lg[N_CLS];
  float lm = -1e30f;
  #pragma unroll
  for (int c = 0; c < N_CLS; ++c) {
    lg[c] = acc[c] + eb3[j * N_CLS + c];
    lm = fmaxf(lm, lg[c]);
  }
  float es = 0.f;
  #pragma unroll
  for (int c = 0; c < N_CLS; ++c) es += __expf(lg[c] - lm);
  float lse = lm + __logf(es);

  float o[N_CLS];
  #pragma unroll
  for (int c = 0; c < N_CLS; ++c) o[c] = gp * (lg[c] - lse);
  #pragma unroll
  for (int c = 0; c < N_CLS; ++c) {
    o[c] += __shfl_xor(o[c], 1);
    o[c] += __shfl_xor(o[c], 2);
    o[c] += __shfl_xor(o[c], 4);
  }

  gate_out[row * N_EXP + j] = gp;
  if (j == 0) {
    #pragma unroll
    for (int c = 0; c < N_CLS; ++c) out[row * N_CLS + c] = o[c];
  }
}

// ---------------------------------------------------------------------------
extern "C" void kernel_launch(void* const* d_in, const int* in_sizes, int n_in,
                              void* d_out, int out_size, void* d_ws, size_t ws_size,
                              hipStream_t stream) {
  const float* fs  = (const float*)d_in[0];
  const float* fp  = (const float*)d_in[1];
  const float* gW1 = (const float*)d_in[2];
  const float* gb1 = (const float*)d_in[3];
  const float* gW2 = (const float*)d_in[4];
  const float* gb2 = (const float*)d_in[5];
  const float* gW3 = (const float*)d_in[6];
  const float* gb3 = (const float*)d_in[7];
  const float* eW1 = (const float*)d_in[8];
  const float* eb1 = (const float*)d_in[9];
  const float* eW2 = (const float*)d_in[10];
  const float* eb2 = (const float*)d_in[11];
  const float* eW3 = (const float*)d_in[12];
  const float* eb3 = (const float*)d_in[13];
  float* out = (float*)d_out;                   // [B,10] then [B,8]

  // workspace layout (bytes):
  //   X   : 0          .. 67,108,864   (B*2048 bf16)  -- aliased by H2 later
  //   W1T : 67,108,864 .. 85,983,232   (4608*2048 bf16)
  //   W2T : 85,983,232 .. 87,162,880   (1152*512 bf16)
  //   H1  : 87,162,880 .. 238,157,824  (B*4608 bf16)
  char* ws = (char*)d_ws;
  __hip_bfloat16* X   = (__hip_bfloat16*)ws;
  __hip_bfloat16* H2  = X;   // alias: X dead after gemm1, H2 fits inside
  __hip_bfloat16* W1T = (__hip_bfloat16*)(ws + 67108864);
  __hip_bfloat16* W2T = (__hip_bfloat16*)(ws + 85983232);
  __hip_bfloat16* H1  = (__hip_bfloat16*)(ws + 87162880);

  convert_features_kernel<<<2048, 256, 0, stream>>>(fs, fp, X);
  transpose_convert_kernel<<<dim3(DIN / 32, N1 / 32), dim3(32, 8), 0, stream>>>(
      eW1, gW1, DIN, H1_SZ, N_EXP, W1T);
  transpose_convert_kernel<<<dim3(H1_SZ / 32, N2 / 32), dim3(32, 8), 0, stream>>>(
      eW2, gW2, H1_SZ, H2_SZ, N_EXP, W2T);
  gemm1_kernel8<<<dim3((N1 / 256) * (B_SZ / 256)), 512, 0, stream>>>(
      X, W1T, eb1, gb1, H1);
  gemm2_kernel<<<dim3(1, B_SZ / 128, N_EXP + 1), 256, 0, stream>>>(H1, W2T, eb2, gb2, H2);
  layer3_kernel<<<B_SZ / 32, 256, 0, stream>>>(H2, gW3, gb3, eW3, eb3,
                                               out, out + (size_t)B_SZ * N_CLS);
}

// Round 3
// 625.956 us; speedup vs baseline: 1.0146x; 1.0146x over previous
//
#include <hip/hip_runtime.h>
#include <hip/hip_bf16.h>

// Problem constants
#define B_SZ   16384
#define DIN    2048
#define H1_SZ  512
#define H2_SZ  128
#define N_EXP  8
#define N_CLS  10
#define N1     4608   // 8*512 experts + 512 gate
#define N2     1152   // 8*128 experts + 128 gate

typedef __attribute__((ext_vector_type(8))) __bf16 bf16x8;
typedef __attribute__((ext_vector_type(4))) float  floatx4;
typedef __attribute__((ext_vector_type(4))) short  short4v;
typedef __attribute__((ext_vector_type(8))) short  short8v;

__device__ __forceinline__ float bf2f(short s) {
  unsigned int u = ((unsigned int)(unsigned short)s) << 16;
  float f; __builtin_memcpy(&f, &u, 4); return f;
}

// ---------------------------------------------------------------------------
// Prep 1: features = concat(fs, fp) -> bf16 X[B][DIN]
// ---------------------------------------------------------------------------
__global__ void convert_features_kernel(const float* __restrict__ fs,
                                        const float* __restrict__ fp,
                                        __hip_bfloat16* __restrict__ X) {
  const int nf4 = B_SZ * (DIN / 4);          // 8,388,608 float4 chunks
  const float4* fs4 = (const float4*)fs;
  const float4* fp4 = (const float4*)fp;
  for (int i = blockIdx.x * blockDim.x + threadIdx.x; i < nf4;
       i += gridDim.x * blockDim.x) {
    int c = i & 511;                         // DIN/4 = 512 chunks per row
    int row = i >> 9;
    float4 v = (c < 256) ? fs4[(size_t)row * 256 + c]
                         : fp4[(size_t)row * 256 + (c - 256)];
    union { short4v v4; __hip_bfloat16 h[4]; } u;
    u.h[0] = __float2bfloat16(v.x);
    u.h[1] = __float2bfloat16(v.y);
    u.h[2] = __float2bfloat16(v.z);
    u.h[3] = __float2bfloat16(v.w);
    *(short4v*)(X + (size_t)i * 4) = u.v4;
  }
}

// ---------------------------------------------------------------------------
// Prep 2: transpose-convert weights to B^T layout (rows = n, stride K), bf16.
// ---------------------------------------------------------------------------
__global__ void transpose_convert_kernel(const float* __restrict__ expert_src,
                                         const float* __restrict__ gate_src,
                                         int K, int H, int E,
                                         __hip_bfloat16* __restrict__ out) {
  __shared__ float t[32][33];
  int k0 = blockIdx.x * 32;
  int n0 = blockIdx.y * 32;   // 32 | H, so a tile never straddles experts
  int e = n0 / H;
  const float* src; int h0;
  if (e < E) { src = expert_src + (size_t)e * K * H; h0 = n0 - e * H; }
  else       { src = gate_src;                       h0 = n0 - E * H; }
  int tx = threadIdx.x, ty = threadIdx.y;
  #pragma unroll
  for (int j = 0; j < 4; ++j) {
    int r = ty + j * 8;
    t[r][tx] = src[(size_t)(k0 + r) * H + h0 + tx];
  }
  __syncthreads();
  #pragma unroll
  for (int j = 0; j < 4; ++j) {
    int r = ty + j * 8;
    out[(size_t)(n0 + r) * K + k0 + tx] = __float2bfloat16(t[tx][r]);
  }
}

// ---------------------------------------------------------------------------
// gemm1: 256x256-tile, 8-wave (2Mx4N), 8-phase schedule, counted vmcnt.
//
// LDS: 8 sub-tiles of [256 rows][32 k] bf16 (16 KB each, 128 KB total):
//   sub = buf*4 + mat*2 + ks   (buf: K-tile parity; mat: 0=A,1=B; ks: K-half)
// Swizzle: within a row (64 B = 4 chunks of 16 B), stored slot cs holds
// logical chunk cs ^ ((row>>1)&3). global_load_lds dest stays linear (HW
// constraint); only the per-lane GLOBAL source address is permuted (within an
// aligned 64 B segment, so coalescing is preserved). Fragment ds_read_b128
// reads are then bank-balanced (R0/R2-verified: SQ_LDS_BANK_CONFLICT == 0).
//
// Phase structure (R3: compiler-scheduled interior — this is the m196 lever):
//   { ds_read frags ; issue 1 stage_sub ; s_waitcnt vmcnt(8) ; s_barrier ;
//     setprio(1) 16xMFMA setprio(0)   <- compiler inserts PER-USE lgkm waits,
//                                        so early MFMAs overlap late ds_reads
//     s_waitcnt lgkmcnt(0) ;          <- WAR fence only: all my reads done
//     s_barrier }                        before I signal barrier2
// R2 post-mortem: placing lgkmcnt(0)+sched_barrier(0) BEFORE the MFMA cluster
// serialized the 8-wave LDS burst (~500 cyc) with the MFMA burst (~620 cyc)
// -> 43% MfmaUtil. The ds_reads are plain C++ loads, so the compiler tracks
// def-use and emits fine-grained lgkmcnt itself (rule #18 does not apply).
// Invariants (unchanged from R2, verified over the stage queue):
//  * PUBLISH: a tile staged at phase p is completed by the vmcnt(8) at phase
//    p+4 and first ds_read at p+5/p+6 — always >= 1 vmcnt+barrier ahead, for
//    every wave.
//  * WAR: trailing lgkmcnt(0) before barrier2; restaging of a region is
//    issued only in a phase after its readers' barrier2.
//  * T4: the load queue never drains to 0 in the main loop (raw s_barrier).
// ---------------------------------------------------------------------------
__device__ __forceinline__ void stage_sub(
    const __hip_bfloat16* __restrict__ src, int ld, int row0, int kofs,
    __hip_bfloat16* dst, int tid) {
  #pragma unroll
  for (int j = 0; j < 2; ++j) {
    int c = j * 512 + tid;                 // chunk 0..1023 (16 B each)
    int r = c >> 2;                        // row 0..255
    int cl = (c & 3) ^ ((r >> 1) & 3);     // logical k-chunk for this slot
    __builtin_amdgcn_global_load_lds(
        (const __attribute__((address_space(1))) unsigned int*)(
            src + (size_t)(row0 + r) * ld + kofs + cl * 8),
        (__attribute__((address_space(3))) unsigned int*)(dst + c * 8),
        16, 0, 0);
  }
}

__device__ __forceinline__ bf16x8 ldsfrag(const __hip_bfloat16* sub, int r, int lquad) {
  int slot = lquad ^ ((r >> 1) & 3);
  return *(const bf16x8*)(sub + r * 32 + slot * 8);
}

template <bool RDB, int MH>
__device__ __forceinline__ void phase8(
    const __hip_bfloat16* Asub, const __hip_bfloat16* Bsub,
    floatx4 (&acc)[8][4], bf16x8 (&b)[4],
    int wm, int wn, int lrow, int lquad,
    const __hip_bfloat16* __restrict__ ssrc, int sld, int srow0, int skofs,
    __hip_bfloat16* sdst, int tid) {
  bf16x8 a[4];
  #pragma unroll
  for (int q = 0; q < 4; ++q)
    a[q] = ldsfrag(Asub, wm + (MH * 4 + q) * 16 + lrow, lquad);
  if (RDB) {
    #pragma unroll
    for (int nt = 0; nt < 4; ++nt)
      b[nt] = ldsfrag(Bsub, wn + nt * 16 + lrow, lquad);
  }
  stage_sub(ssrc, sld, srow0, skofs, sdst, tid);
  asm volatile("s_waitcnt vmcnt(8)" ::: "memory");   // publish-for-NEXT-phase
  __builtin_amdgcn_s_barrier();
  __builtin_amdgcn_s_setprio(1);
  #pragma unroll
  for (int q = 0; q < 4; ++q)
    #pragma unroll
    for (int nt = 0; nt < 4; ++nt)
      acc[MH * 4 + q][nt] = __builtin_amdgcn_mfma_f32_16x16x32_bf16(
          a[q], b[nt], acc[MH * 4 + q][nt], 0, 0, 0);
  __builtin_amdgcn_s_setprio(0);
  asm volatile("s_waitcnt lgkmcnt(0)" ::: "memory"); // WAR fence before bar2
  __builtin_amdgcn_s_barrier();
}

__global__ __launch_bounds__(512, 2) void gemm1_kernel8(
    const __hip_bfloat16* __restrict__ X, const __hip_bfloat16* __restrict__ W1T,
    const float* __restrict__ eb1, const float* __restrict__ gb1,
    __hip_bfloat16* __restrict__ H1) {
  __shared__ __align__(16) __hip_bfloat16 lds[8][256 * 32];

  const int tid  = threadIdx.x;
  const int lane = tid & 63;
  const int wave = tid >> 6;
  const int wm   = (wave >> 2) * 128;    // 0 or 128
  const int wn   = (wave & 3) * 64;      // 0,64,128,192
  const int lrow  = lane & 15;
  const int lquad = lane >> 4;

  // bijective XCD swizzle (1152 % 8 == 0): each XCD gets a contiguous run of
  // tiles -> A/B panels stay hot in that XCD's L2.
  int flat = blockIdx.x;
  int swz  = (flat & 7) * ((int)gridDim.x >> 3) + (flat >> 3);
  int m0 = (swz / (N1 / 256)) * 256;
  int n0 = (swz % (N1 / 256)) * 256;

  floatx4 acc[8][4] = {};
  bf16x8 b[4];

  const int KT = DIN / 64;   // 32 K-tiles

  // prologue: tile0 (4 subs) + tile1 ks0 (2 subs) = 12 loads in flight.
  // Queue order: lds[0], lds[2], lds[1], lds[3], lds[4], lds[6].
  stage_sub(X,   DIN, m0, 0,  lds[0], tid);  // A buf0 ks0  <- tile0
  stage_sub(W1T, DIN, n0, 0,  lds[2], tid);  // B buf0 ks0
  stage_sub(X,   DIN, m0, 32, lds[1], tid);  // A buf0 ks1
  stage_sub(W1T, DIN, n0, 32, lds[3], tid);  // B buf0 ks1
  stage_sub(X,   DIN, m0, 64, lds[4], tid);  // A buf1 ks0  <- tile1
  stage_sub(W1T, DIN, n0, 64, lds[6], tid);  // B buf1 ks0
  asm volatile("s_waitcnt vmcnt(8)" ::: "memory");  // completes lds[0], lds[2]
  __builtin_amdgcn_s_barrier();

  for (int i = 0; i < KT / 2; ++i) {
    int T  = 2 * i;
    int k1 = (T + 1) * 64;                     // tile T+1 (always valid)
    int k2 = min(T + 2, KT - 1) * 64;          // tile T+2 (clamped; the
    int k3 = min(T + 3, KT - 1) * 64;          //  clamped stages are never read)
    phase8<true,  0>(lds[0], lds[2], acc, b, wm, wn, lrow, lquad,
                     X,   DIN, m0, k1 + 32, lds[5], tid);   // ph1
    phase8<false, 1>(lds[0], lds[2], acc, b, wm, wn, lrow, lquad,
                     W1T, DIN, n0, k1 + 32, lds[7], tid);   // ph2
    phase8<true,  0>(lds[1], lds[3], acc, b, wm, wn, lrow, lquad,
                     X,   DIN, m0, k2,      lds[0], tid);   // ph3
    phase8<false, 1>(lds[1], lds[3], acc, b, wm, wn, lrow, lquad,
                     W1T, DIN, n0, k2,      lds[2], tid);   // ph4
    phase8<true,  0>(lds[4], lds[6], acc, b, wm, wn, lrow, lquad,
                     X,   DIN, m0, k2 + 32, lds[1], tid);   // ph5
    phase8<false, 1>(lds[4], lds[6], acc, b, wm, wn, lrow, lquad,
                     W1T, DIN, n0, k2 + 32, lds[3], tid);   // ph6
    phase8<true,  0>(lds[5], lds[7], acc, b, wm, wn, lrow, lquad,
                     X,   DIN, m0, k3,      lds[4], tid);   // ph7
    phase8<false, 1>(lds[5], lds[7], acc, b, wm, wn, lrow, lquad,
                     W1T, DIN, n0, k3,      lds[6], tid);   // ph8
  }

  // epilogue: bias + relu -> bf16. C/D layout: col = lane&15, row = quad*4+r.
  // n0 is a multiple of 256; expert/gate bias boundary at 4096 = 16*256, so a
  // block never straddles it.
  const float* bias = (n0 < N_EXP * H1_SZ) ? (eb1 + n0) : (gb1 + (n0 - N_EXP * H1_SZ));
  #pragma unroll
  for (int nt = 0; nt < 4; ++nt) {
    int col = wn + nt * 16 + lrow;
    float bv = bias[col];
    #pragma unroll
    for (int mt = 0; mt < 8; ++mt) {
      #pragma unroll
      for (int r = 0; r < 4; ++r) {
        int row = m0 + wm + mt * 16 + lquad * 4 + r;
        float v = acc[mt][nt][r] + bv;
        v = v > 0.f ? v : 0.f;
        H1[(size_t)row * N1 + n0 + col] = __float2bfloat16(v);
      }
    }
  }
}

// ---------------------------------------------------------------------------
// 128x128 MFMA GEMM core (kept for gemm2, whose N-slice is only 128 wide).
// ---------------------------------------------------------------------------
__device__ __forceinline__ void gemm_core(
    const __hip_bfloat16* __restrict__ A,  int lda,
    const __hip_bfloat16* __restrict__ BT, int K,
    const float* __restrict__ bias,
    __hip_bfloat16* __restrict__ O, int ldo) {
  __shared__ __align__(16) __hip_bfloat16 As[128 * 64];
  __shared__ __align__(16) __hip_bfloat16 Bs[128 * 64];

  const int tid  = threadIdx.x;
  const int lane = tid & 63;
  const int wave = tid >> 6;
  const int wm   = (wave >> 1) * 64;
  const int wn   = (wave & 1) * 64;
  const int lrow  = lane & 15;
  const int lquad = lane >> 4;

  floatx4 acc[4][4] = {};

  for (int k0 = 0; k0 < K; k0 += 64) {
    #pragma unroll
    for (int j = 0; j < 4; ++j) {
      int chunk = j * 256 + tid;       // 0..1023 chunks of 8 bf16 (16 B)
      int mi = chunk >> 3;             // tile row 0..127
      int cs = chunk & 7;              // stored chunk slot 0..7
      int cl = cs ^ (mi & 7);          // logical k-chunk held in this slot
      __builtin_amdgcn_global_load_lds(
          (const __attribute__((address_space(1))) unsigned int*)(A + (size_t)mi * lda + k0 + cl * 8),
          (__attribute__((address_space(3))) unsigned int*)(As + chunk * 8),
          16, 0, 0);
      __builtin_amdgcn_global_load_lds(
          (const __attribute__((address_space(1))) unsigned int*)(BT + (size_t)mi * K + k0 + cl * 8),
          (__attribute__((address_space(3))) unsigned int*)(Bs + chunk * 8),
          16, 0, 0);
    }
    __syncthreads();
    #pragma unroll
    for (int ks = 0; ks < 2; ++ks) {
      bf16x8 a[4], b[4];
      #pragma unroll
      for (int t = 0; t < 4; ++t) {
        int ar = wm + t * 16 + lrow;
        int br = wn + t * 16 + lrow;
        int ca = (ks * 4 + lquad) ^ (ar & 7);   // swizzled chunk slot
        int cb = (ks * 4 + lquad) ^ (br & 7);
        a[t] = *(const bf16x8*)(As + ar * 64 + ca * 8);
        b[t] = *(const bf16x8*)(Bs + br * 64 + cb * 8);
      }
      #pragma unroll
      for (int mt = 0; mt < 4; ++mt)
        #pragma unroll
        for (int nt = 0; nt < 4; ++nt)
          acc[mt][nt] = __builtin_amdgcn_mfma_f32_16x16x32_bf16(
              a[mt], b[nt], acc[mt][nt], 0, 0, 0);
    }
    __syncthreads();
  }

  #pragma unroll
  for (int nt = 0; nt < 4; ++nt) {
    int col = wn + nt * 16 + lrow;
    float bv = bias[col];
    #pragma unroll
    for (int mt = 0; mt < 4; ++mt) {
      #pragma unroll
      for (int r = 0; r < 4; ++r) {
        int row = wm + mt * 16 + lquad * 4 + r;
        float v = acc[mt][nt][r] + bv;
        v = v > 0.f ? v : 0.f;
        O[(size_t)row * ldo + col] = __float2bfloat16(v);
      }
    }
  }
}

// Layer 2: per z in 0..8: H1 block [B][512] @ W2T[z]^T -> relu -> H2 block [B][128]
__global__ __launch_bounds__(256, 2) void gemm2_kernel(
    const __hip_bfloat16* __restrict__ H1, const __hip_bfloat16* __restrict__ W2T,
    const float* __restrict__ eb2, const float* __restrict__ gb2,
    __hip_bfloat16* __restrict__ H2) {
  int m0 = blockIdx.y * 128;
  int z  = blockIdx.z;                 // 0..7 experts, 8 = gate
  const float* bias = (z < N_EXP) ? (eb2 + z * H2_SZ) : gb2;
  gemm_core(H1 + (size_t)m0 * N1 + z * H1_SZ, N1,
            W2T + (size_t)z * H2_SZ * H1_SZ, H1_SZ,
            bias,
            H2 + (size_t)m0 * N2 + z * H2_SZ, N2);
}

// ---------------------------------------------------------------------------
// Layer 3 fused: gate logits + softmax, expert logits + log_softmax, weighted
// sum. 8 threads per batch row (thread j = expert j and gate col j).
// ---------------------------------------------------------------------------
__global__ __launch_bounds__(256) void layer3_kernel(
    const __hip_bfloat16* __restrict__ H2,
    const float* __restrict__ gW3, const float* __restrict__ gb3,
    const float* __restrict__ eW3, const float* __restrict__ eb3,
    float* __restrict__ out, float* __restrict__ gate_out) {
  int tid  = threadIdx.x;
  int j    = tid & 7;
  int rloc = tid >> 3;                             // 0..31
  long row = (long)blockIdx.x * 32 + rloc;
  const __hip_bfloat16* hrow = H2 + row * N2;

  float accg = 0.f;
  float acc[N_CLS];
  #pragma unroll
  for (int c = 0; c < N_CLS; ++c) acc[c] = 0.f;

  #pragma unroll 4
  for (int k8 = 0; k8 < 16; ++k8) {
    short8v hg8 = *(const short8v*)(hrow + N_EXP * H2_SZ + k8 * 8);  // gate block
    short8v he8 = *(const short8v*)(hrow + j * H2_SZ + k8 * 8);      // expert j
    #pragma unroll
    for (int t = 0; t < 8; ++t) {
      int k = k8 * 8 + t;
      float hg = bf2f(hg8[t]);
      float he = bf2f(he8[t]);
      accg += hg * gW3[k * N_EXP + j];
      const float* w = eW3 + (size_t)(j * H2_SZ + k) * N_CLS;
      #pragma unroll
      for (int c = 0; c < N_CLS; ++c) acc[c] += he * w[c];
    }
  }

  // gate softmax across the 8 threads of this row
  float gj = accg + gb3[j];
  float mx = gj;
  mx = fmaxf(mx, __shfl_xor(mx, 1));
  mx = fmaxf(mx, __shfl_xor(mx, 2));
  mx = fmaxf(mx, __shfl_xor(mx, 4));
  float ex = __expf(gj - mx);
  float s = ex;
  s += __shfl_xor(s, 1);
  s += __shfl_xor(s, 2);
  s += __shfl_xor(s, 4);
  float gp = ex / s;

  // expert-local log_softmax over 10 classes
  float lg[N_CLS];
  float lm = -1e30f;
  #pragma unroll
  for (int c = 0; c < N_CLS; ++c) {
    lg[c] = acc[c] + eb3[j * N_CLS + c];
    lm = fmaxf(lm, lg[c]);
  }
  float es = 0.f;
  #pragma unroll
  for (int c = 0; c < N_CLS; ++c) es += __expf(lg[c] - lm);
  float lse = lm + __logf(es);

  float o[N_CLS];
  #pragma unroll
  for (int c = 0; c < N_CLS; ++c) o[c] = gp * (lg[c] - lse);
  #pragma unroll
  for (int c = 0; c < N_CLS; ++c) {
    o[c] += __shfl_xor(o[c], 1);
    o[c] += __shfl_xor(o[c], 2);
    o[c] += __shfl_xor(o[c], 4);
  }

  gate_out[row * N_EXP + j] = gp;
  if (j == 0) {
    #pragma unroll
    for (int c = 0; c < N_CLS; ++c) out[row * N_CLS + c] = o[c];
  }
}

// ---------------------------------------------------------------------------
extern "C" void kernel_launch(void* const* d_in, const int* in_sizes, int n_in,
                              void* d_out, int out_size, void* d_ws, size_t ws_size,
                              hipStream_t stream) {
  const float* fs  = (const float*)d_in[0];
  const float* fp  = (const float*)d_in[1];
  const float* gW1 = (const float*)d_in[2];
  const float* gb1 = (const float*)d_in[3];
  const float* gW2 = (const float*)d_in[4];
  const float* gb2 = (const float*)d_in[5];
  const float* gW3 = (const float*)d_in[6];
  const float* gb3 = (const float*)d_in[7];
  const float* eW1 = (const float*)d_in[8];
  const float* eb1 = (const float*)d_in[9];
  const float* eW2 = (const float*)d_in[10];
  const float* eb2 = (const float*)d_in[11];
  const float* eW3 = (const float*)d_in[12];
  const float* eb3 = (const float*)d_in[13];
  float* out = (float*)d_out;                   // [B,10] then [B,8]

  // workspace layout (bytes):
  //   X   : 0          .. 67,108,864   (B*2048 bf16)  -- aliased by H2 later
  //   W1T : 67,108,864 .. 85,983,232   (4608*2048 bf16)
  //   W2T : 85,983,232 .. 87,162,880   (1152*512 bf16)
  //   H1  : 87,162,880 .. 238,157,824  (B*4608 bf16)
  char* ws = (char*)d_ws;
  __hip_bfloat16* X   = (__hip_bfloat16*)ws;
  __hip_bfloat16* H2  = X;   // alias: X dead after gemm1, H2 fits inside
  __hip_bfloat16* W1T = (__hip_bfloat16*)(ws + 67108864);
  __hip_bfloat16* W2T = (__hip_bfloat16*)(ws + 85983232);
  __hip_bfloat16* H1  = (__hip_bfloat16*)(ws + 87162880);

  convert_features_kernel<<<2048, 256, 0, stream>>>(fs, fp, X);
  transpose_convert_kernel<<<dim3(DIN / 32, N1 / 32), dim3(32, 8), 0, stream>>>(
      eW1, gW1, DIN, H1_SZ, N_EXP, W1T);
  transpose_convert_kernel<<<dim3(H1_SZ / 32, N2 / 32), dim3(32, 8), 0, stream>>>(
      eW2, gW2, H1_SZ, H2_SZ, N_EXP, W2T);
  gemm1_kernel8<<<dim3((N1 / 256) * (B_SZ / 256)), 512, 0, stream>>>(
      X, W1T, eb1, gb1, H1);
  gemm2_kernel<<<dim3(1, B_SZ / 128, N_EXP + 1), 256, 0, stream>>>(H1, W2T, eb2, gb2, H2);
  layer3_kernel<<<B_SZ / 32, 256, 0, stream>>>(H2, gW3, gb3, eW3, eb3,
                                               out, out + (size_t)B_SZ * N_CLS);
}

// Round 4
// 617.142 us; speedup vs baseline: 1.0291x; 1.0143x over previous
//
#include <hip/hip_runtime.h>
#include <hip/hip_bf16.h>

// Problem constants
#define B_SZ   16384
#define DIN    2048
#define H1_SZ  512
#define H2_SZ  128
#define N_EXP  8
#define N_CLS  10
#define N1     4608   // 8*512 experts + 512 gate
#define N2     1152   // 8*128 experts + 128 gate

typedef __attribute__((ext_vector_type(8))) __bf16 bf16x8;
typedef __attribute__((ext_vector_type(4))) float  floatx4;
typedef __attribute__((ext_vector_type(4))) short  short4v;
typedef __attribute__((ext_vector_type(8))) short  short8v;

__device__ __forceinline__ float bf2f(short s) {
  unsigned int u = ((unsigned int)(unsigned short)s) << 16;
  float f; __builtin_memcpy(&f, &u, 4); return f;
}

// ---------------------------------------------------------------------------
// Prep 1: features = concat(fs, fp) -> bf16 X[B][DIN]
// ---------------------------------------------------------------------------
__global__ void convert_features_kernel(const float* __restrict__ fs,
                                        const float* __restrict__ fp,
                                        __hip_bfloat16* __restrict__ X) {
  const int nf4 = B_SZ * (DIN / 4);          // 8,388,608 float4 chunks
  const float4* fs4 = (const float4*)fs;
  const float4* fp4 = (const float4*)fp;
  for (int i = blockIdx.x * blockDim.x + threadIdx.x; i < nf4;
       i += gridDim.x * blockDim.x) {
    int c = i & 511;                         // DIN/4 = 512 chunks per row
    int row = i >> 9;
    float4 v = (c < 256) ? fs4[(size_t)row * 256 + c]
                         : fp4[(size_t)row * 256 + (c - 256)];
    union { short4v v4; __hip_bfloat16 h[4]; } u;
    u.h[0] = __float2bfloat16(v.x);
    u.h[1] = __float2bfloat16(v.y);
    u.h[2] = __float2bfloat16(v.z);
    u.h[3] = __float2bfloat16(v.w);
    *(short4v*)(X + (size_t)i * 4) = u.v4;
  }
}

// ---------------------------------------------------------------------------
// Prep 2: transpose-convert weights to B^T layout (rows = n, stride K), bf16.
// ---------------------------------------------------------------------------
__global__ void transpose_convert_kernel(const float* __restrict__ expert_src,
                                         const float* __restrict__ gate_src,
                                         int K, int H, int E,
                                         __hip_bfloat16* __restrict__ out) {
  __shared__ float t[32][33];
  int k0 = blockIdx.x * 32;
  int n0 = blockIdx.y * 32;   // 32 | H, so a tile never straddles experts
  int e = n0 / H;
  const float* src; int h0;
  if (e < E) { src = expert_src + (size_t)e * K * H; h0 = n0 - e * H; }
  else       { src = gate_src;                       h0 = n0 - E * H; }
  int tx = threadIdx.x, ty = threadIdx.y;
  #pragma unroll
  for (int j = 0; j < 4; ++j) {
    int r = ty + j * 8;
    t[r][tx] = src[(size_t)(k0 + r) * H + h0 + tx];
  }
  __syncthreads();
  #pragma unroll
  for (int j = 0; j < 4; ++j) {
    int r = ty + j * 8;
    out[(size_t)(n0 + r) * K + k0 + tx] = __float2bfloat16(t[tx][r]);
  }
}

// ---------------------------------------------------------------------------
// gemm1: 256x256-tile, 8-wave (2Mx4N), rotated 8-slot software pipeline.
//
// R2/R3 post-mortem: phase skeleton {ds_reads; bar; MFMA; bar} strictly
// alternates the LDS pipe (~576 cyc: 48 wave ds_read_b128 x 12 cyc) and the
// matrix pipe (~620 cyc: 32 MFMA/SIMD x 19.4 cyc) -> 1340 cyc/phase, 43%
// MfmaUtil, for BOTH lgkm placements. Fix: rotate the pipeline — issue the
// NEXT slot's ds_reads before the CURRENT slot's MFMA burst, one barrier per
// slot. MFMAs are register-only, so they need no barrier protection; the
// matrix pipe drains while the LDS pipe serves the next slot's reads.
//
// LDS: 8 sub-tiles of [256 rows][32 k] bf16 (16 KB each, 128 KB total):
//   sub = buf*4 + mat*2 + ks. Swizzle (R0-verified, conflict-free): within a
//   row (4 chunks of 16 B), stored slot cs holds logical chunk
//   cs ^ ((row>>1)&3); global_load_lds dest linear, global source permuted
//   within an aligned 64 B segment.
//
// Slot structure (one barrier per slot):
//   { s_waitcnt vmcnt(6) + s_barrier   <- single asm: publish tile staged 4
//                                         slots ago; nothing slips between
//     ds_read frags for slot p+1 (into the OTHER frag buffer)
//     stage_sub (1 per slot)
//     setprio(1) 16xMFMA on slot-p frags setprio(0)
//     s_waitcnt lgkmcnt(0) }           <- own reads drained before next
//                                         barrier => restage WAR-safe
// Verified invariants (hand-traced over the 8-slot ring):
//  * PUBLISH: tile staged at slot q completes at vmcnt(6) of q+4, published
//    by q+4's barrier, first read inside q+5 (serving q+6) — for the
//    tightest cases (lds[6] pro-staged, lds[0]/lds[2] restaged at s3/s4,
//    read inside s8) the margin is exactly one barrier. Safe for all waves.
//  * WAR: readers of a region drain at their slot's lgkmcnt(0); the restage
//    is >= 2 barriers later.
//  * T4: vmcnt never drains to 0 in the loop (8 loads = 4 stage_subs in
//    flight at every slot top).
// Frag double-buffering: aX/aY alternate per slot; bX/bY per slot-pair
// (b reloaded only in even slots). All names static (rule #20).
// ---------------------------------------------------------------------------
__device__ __forceinline__ void stage_sub(
    const __hip_bfloat16* __restrict__ src, int row0, int kofs,
    __hip_bfloat16* dst, int tid) {
  #pragma unroll
  for (int j = 0; j < 2; ++j) {
    int c = j * 512 + tid;                 // chunk 0..1023 (16 B each)
    int r = c >> 2;                        // row 0..255
    int cl = (c & 3) ^ ((r >> 1) & 3);     // logical k-chunk for this slot
    __builtin_amdgcn_global_load_lds(
        (const __attribute__((address_space(1))) unsigned int*)(
            src + (size_t)(row0 + r) * DIN + kofs + cl * 8),
        (__attribute__((address_space(3))) unsigned int*)(dst + c * 8),
        16, 0, 0);
  }
}

__device__ __forceinline__ bf16x8 ldsfrag(const __hip_bfloat16* sub, int r, int lquad) {
  int slot = lquad ^ ((r >> 1) & 3);
  return *(const bf16x8*)(sub + r * 32 + slot * 8);
}

// MHC: M-half consumed by this slot's MFMA. MHN: M-half loaded for next slot.
template <int MHC, int MHN, bool LOADB>
__device__ __forceinline__ void pipe_slot(
    floatx4 (&acc)[8][4],
    bf16x8 (&a_cur)[4], bf16x8 (&b_cur)[4],
    bf16x8 (&a_nxt)[4], bf16x8 (&b_nxt)[4],
    const __hip_bfloat16* An, const __hip_bfloat16* Bn,
    int wm, int wn, int lrow, int lquad,
    const __hip_bfloat16* __restrict__ ssrc, int srow0, int skofs,
    __hip_bfloat16* sdst, int tid) {
  asm volatile("s_waitcnt vmcnt(6)\n\ts_barrier" ::: "memory");
  #pragma unroll
  for (int q = 0; q < 4; ++q)
    a_nxt[q] = ldsfrag(An, wm + (MHN * 4 + q) * 16 + lrow, lquad);
  if (LOADB) {
    #pragma unroll
    for (int nt = 0; nt < 4; ++nt)
      b_nxt[nt] = ldsfrag(Bn, wn + nt * 16 + lrow, lquad);
  }
  stage_sub(ssrc, srow0, skofs, sdst, tid);
  __builtin_amdgcn_s_setprio(1);
  #pragma unroll
  for (int q = 0; q < 4; ++q)
    #pragma unroll
    for (int nt = 0; nt < 4; ++nt)
      acc[MHC * 4 + q][nt] = __builtin_amdgcn_mfma_f32_16x16x32_bf16(
          a_cur[q], b_cur[nt], acc[MHC * 4 + q][nt], 0, 0, 0);
  __builtin_amdgcn_s_setprio(0);
  asm volatile("s_waitcnt lgkmcnt(0)" ::: "memory");
}

__global__ __launch_bounds__(512, 2) void gemm1_kernel8(
    const __hip_bfloat16* __restrict__ X, const __hip_bfloat16* __restrict__ W1T,
    const float* __restrict__ eb1, const float* __restrict__ gb1,
    __hip_bfloat16* __restrict__ H1) {
  __shared__ __align__(16) __hip_bfloat16 lds[8][256 * 32];

  const int tid  = threadIdx.x;
  const int lane = tid & 63;
  const int wave = tid >> 6;
  const int wm   = (wave >> 2) * 128;    // 0 or 128
  const int wn   = (wave & 3) * 64;      // 0,64,128,192
  const int lrow  = lane & 15;
  const int lquad = lane >> 4;

  // bijective XCD swizzle (1152 % 8 == 0): each XCD gets a contiguous run of
  // tiles -> A/B panels stay hot in that XCD's L2.
  int flat = blockIdx.x;
  int swz  = (flat & 7) * ((int)gridDim.x >> 3) + (flat >> 3);
  int m0 = (swz / (N1 / 256)) * 256;
  int n0 = (swz % (N1 / 256)) * 256;

  floatx4 acc[8][4] = {};
  bf16x8 aX[4], aY[4], bX[4], bY[4];

  const int KT = DIN / 64;   // 32 K-tiles

  // prologue: tile0 (4 subs) + tile1 ks0 (2 subs) = 12 loads in flight.
  // Queue order: lds[0], lds[2], lds[1], lds[3], lds[4], lds[6].
  stage_sub(X,   m0, 0,  lds[0], tid);  // A buf0 ks0  <- tile0
  stage_sub(W1T, n0, 0,  lds[2], tid);  // B buf0 ks0
  stage_sub(X,   m0, 32, lds[1], tid);  // A buf0 ks1
  stage_sub(W1T, n0, 32, lds[3], tid);  // B buf0 ks1
  stage_sub(X,   m0, 64, lds[4], tid);  // A buf1 ks0  <- tile1
  stage_sub(W1T, n0, 64, lds[6], tid);  // B buf1 ks0
  asm volatile("s_waitcnt vmcnt(8)\n\ts_barrier" ::: "memory"); // lds[0],[2] live
  #pragma unroll
  for (int q = 0; q < 4; ++q)
    aX[q] = ldsfrag(lds[0], wm + q * 16 + lrow, lquad);      // slot1 frags (MH0)
  #pragma unroll
  for (int nt = 0; nt < 4; ++nt)
    bX[nt] = ldsfrag(lds[2], wn + nt * 16 + lrow, lquad);
  asm volatile("s_waitcnt lgkmcnt(0)" ::: "memory");

  for (int i = 0; i < KT / 2; ++i) {
    int T  = 2 * i;
    int k1 = (T + 1) * 64;                     // tile T+1 (always valid)
    int k2 = min(T + 2, KT - 1) * 64;          // tile T+2 (clamped; the
    int k3 = min(T + 3, KT - 1) * 64;          //  clamped stages are never read)
    // slot: <MHC,MHN,LOADB>(acc, a_cur,b_cur, a_nxt,b_nxt, An,Bn, ..., stage)
    pipe_slot<0,1,false>(acc, aX, bX, aY, bY, lds[0], lds[0],
                         wm, wn, lrow, lquad, X,   m0, k1 + 32, lds[5], tid);
    pipe_slot<1,0,true >(acc, aY, bX, aX, bY, lds[1], lds[3],
                         wm, wn, lrow, lquad, W1T, n0, k1 + 32, lds[7], tid);
    pipe_slot<0,1,false>(acc, aX, bY, aY, bX, lds[1], lds[1],
                         wm, wn, lrow, lquad, X,   m0, k2,      lds[0], tid);
    pipe_slot<1,0,true >(acc, aY, bY, aX, bX, lds[4], lds[6],
                         wm, wn, lrow, lquad, W1T, n0, k2,      lds[2], tid);
    pipe_slot<0,1,false>(acc, aX, bX, aY, bY, lds[4], lds[4],
                         wm, wn, lrow, lquad, X,   m0, k2 + 32, lds[1], tid);
    pipe_slot<1,0,true >(acc, aY, bX, aX, bY, lds[5], lds[7],
                         wm, wn, lrow, lquad, W1T, n0, k2 + 32, lds[3], tid);
    pipe_slot<0,1,false>(acc, aX, bY, aY, bX, lds[5], lds[5],
                         wm, wn, lrow, lquad, X,   m0, k3,      lds[4], tid);
    pipe_slot<1,0,true >(acc, aY, bY, aX, bX, lds[0], lds[2],
                         wm, wn, lrow, lquad, W1T, n0, k3,      lds[6], tid);
  }

  // epilogue: bias + relu -> bf16. C/D layout: col = lane&15, row = quad*4+r.
  // n0 is a multiple of 256; expert/gate bias boundary at 4096 = 16*256, so a
  // block never straddles it.
  const float* bias = (n0 < N_EXP * H1_SZ) ? (eb1 + n0) : (gb1 + (n0 - N_EXP * H1_SZ));
  #pragma unroll
  for (int nt = 0; nt < 4; ++nt) {
    int col = wn + nt * 16 + lrow;
    float bv = bias[col];
    #pragma unroll
    for (int mt = 0; mt < 8; ++mt) {
      #pragma unroll
      for (int r = 0; r < 4; ++r) {
        int row = m0 + wm + mt * 16 + lquad * 4 + r;
        float v = acc[mt][nt][r] + bv;
        v = v > 0.f ? v : 0.f;
        H1[(size_t)row * N1 + n0 + col] = __float2bfloat16(v);
      }
    }
  }
}

// ---------------------------------------------------------------------------
// 128x128 MFMA GEMM core (kept for gemm2, whose N-slice is only 128 wide).
// ---------------------------------------------------------------------------
__device__ __forceinline__ void gemm_core(
    const __hip_bfloat16* __restrict__ A,  int lda,
    const __hip_bfloat16* __restrict__ BT, int K,
    const float* __restrict__ bias,
    __hip_bfloat16* __restrict__ O, int ldo) {
  __shared__ __align__(16) __hip_bfloat16 As[128 * 64];
  __shared__ __align__(16) __hip_bfloat16 Bs[128 * 64];

  const int tid  = threadIdx.x;
  const int lane = tid & 63;
  const int wave = tid >> 6;
  const int wm   = (wave >> 1) * 64;
  const int wn   = (wave & 1) * 64;
  const int lrow  = lane & 15;
  const int lquad = lane >> 4;

  floatx4 acc[4][4] = {};

  for (int k0 = 0; k0 < K; k0 += 64) {
    #pragma unroll
    for (int j = 0; j < 4; ++j) {
      int chunk = j * 256 + tid;       // 0..1023 chunks of 8 bf16 (16 B)
      int mi = chunk >> 3;             // tile row 0..127
      int cs = chunk & 7;              // stored chunk slot 0..7
      int cl = cs ^ (mi & 7);          // logical k-chunk held in this slot
      __builtin_amdgcn_global_load_lds(
          (const __attribute__((address_space(1))) unsigned int*)(A + (size_t)mi * lda + k0 + cl * 8),
          (__attribute__((address_space(3))) unsigned int*)(As + chunk * 8),
          16, 0, 0);
      __builtin_amdgcn_global_load_lds(
          (const __attribute__((address_space(1))) unsigned int*)(BT + (size_t)mi * K + k0 + cl * 8),
          (__attribute__((address_space(3))) unsigned int*)(Bs + chunk * 8),
          16, 0, 0);
    }
    __syncthreads();
    #pragma unroll
    for (int ks = 0; ks < 2; ++ks) {
      bf16x8 a[4], b[4];
      #pragma unroll
      for (int t = 0; t < 4; ++t) {
        int ar = wm + t * 16 + lrow;
        int br = wn + t * 16 + lrow;
        int ca = (ks * 4 + lquad) ^ (ar & 7);   // swizzled chunk slot
        int cb = (ks * 4 + lquad) ^ (br & 7);
        a[t] = *(const bf16x8*)(As + ar * 64 + ca * 8);
        b[t] = *(const bf16x8*)(Bs + br * 64 + cb * 8);
      }
      #pragma unroll
      for (int mt = 0; mt < 4; ++mt)
        #pragma unroll
        for (int nt = 0; nt < 4; ++nt)
          acc[mt][nt] = __builtin_amdgcn_mfma_f32_16x16x32_bf16(
              a[mt], b[nt], acc[mt][nt], 0, 0, 0);
    }
    __syncthreads();
  }

  #pragma unroll
  for (int nt = 0; nt < 4; ++nt) {
    int col = wn + nt * 16 + lrow;
    float bv = bias[col];
    #pragma unroll
    for (int mt = 0; mt < 4; ++mt) {
      #pragma unroll
      for (int r = 0; r < 4; ++r) {
        int row = wm + mt * 16 + lquad * 4 + r;
        float v = acc[mt][nt][r] + bv;
        v = v > 0.f ? v : 0.f;
        O[(size_t)row * ldo + col] = __float2bfloat16(v);
      }
    }
  }
}

// Layer 2: per z in 0..8: H1 block [B][512] @ W2T[z]^T -> relu -> H2 block [B][128]
__global__ __launch_bounds__(256, 2) void gemm2_kernel(
    const __hip_bfloat16* __restrict__ H1, const __hip_bfloat16* __restrict__ W2T,
    const float* __restrict__ eb2, const float* __restrict__ gb2,
    __hip_bfloat16* __restrict__ H2) {
  int m0 = blockIdx.y * 128;
  int z  = blockIdx.z;                 // 0..7 experts, 8 = gate
  const float* bias = (z < N_EXP) ? (eb2 + z * H2_SZ) : gb2;
  gemm_core(H1 + (size_t)m0 * N1 + z * H1_SZ, N1,
            W2T + (size_t)z * H2_SZ * H1_SZ, H1_SZ,
            bias,
            H2 + (size_t)m0 * N2 + z * H2_SZ, N2);
}

// ---------------------------------------------------------------------------
// Layer 3 fused: gate logits + softmax, expert logits + log_softmax, weighted
// sum. 8 threads per batch row (thread j = expert j and gate col j).
// ---------------------------------------------------------------------------
__global__ __launch_bounds__(256) void layer3_kernel(
    const __hip_bfloat16* __restrict__ H2,
    const float* __restrict__ gW3, const float* __restrict__ gb3,
    const float* __restrict__ eW3, const float* __restrict__ eb3,
    float* __restrict__ out, float* __restrict__ gate_out) {
  int tid  = threadIdx.x;
  int j    = tid & 7;
  int rloc = tid >> 3;                             // 0..31
  long row = (long)blockIdx.x * 32 + rloc;
  const __hip_bfloat16* hrow = H2 + row * N2;

  float accg = 0.f;
  float acc[N_CLS];
  #pragma unroll
  for (int c = 0; c < N_CLS; ++c) acc[c] = 0.f;

  #pragma unroll 4
  for (int k8 = 0; k8 < 16; ++k8) {
    short8v hg8 = *(const short8v*)(hrow + N_EXP * H2_SZ + k8 * 8);  // gate block
    short8v he8 = *(const short8v*)(hrow + j * H2_SZ + k8 * 8);      // expert j
    #pragma unroll
    for (int t = 0; t < 8; ++t) {
      int k = k8 * 8 + t;
      float hg = bf2f(hg8[t]);
      float he = bf2f(he8[t]);
      accg += hg * gW3[k * N_EXP + j];
      const float* w = eW3 + (size_t)(j * H2_SZ + k) * N_CLS;
      #pragma unroll
      for (int c = 0; c < N_CLS; ++c) acc[c] += he * w[c];
    }
  }

  // gate softmax across the 8 threads of this row
  float gj = accg + gb3[j];
  float mx = gj;
  mx = fmaxf(mx, __shfl_xor(mx, 1));
  mx = fmaxf(mx, __shfl_xor(mx, 2));
  mx = fmaxf(mx, __shfl_xor(mx, 4));
  float ex = __expf(gj - mx);
  float s = ex;
  s += __shfl_xor(s, 1);
  s += __shfl_xor(s, 2);
  s += __shfl_xor(s, 4);
  float gp = ex / s;

  // expert-local log_softmax over 10 classes
  float lg[N_CLS];
  float lm = -1e30f;
  #pragma unroll
  for (int c = 0; c < N_CLS; ++c) {
    lg[c] = acc[c] + eb3[j * N_CLS + c];
    lm = fmaxf(lm, lg[c]);
  }
  float es = 0.f;
  #pragma unroll
  for (int c = 0; c < N_CLS; ++c) es += __expf(lg[c] - lm);
  float lse = lm + __logf(es);

  float o[N_CLS];
  #pragma unroll
  for (int c = 0; c < N_CLS; ++c) o[c] = gp * (lg[c] - lse);
  #pragma unroll
  for (int c = 0; c < N_CLS; ++c) {
    o[c] += __shfl_xor(o[c], 1);
    o[c] += __shfl_xor(o[c], 2);
    o[c] += __shfl_xor(o[c], 4);
  }

  gate_out[row * N_EXP + j] = gp;
  if (j == 0) {
    #pragma unroll
    for (int c = 0; c < N_CLS; ++c) out[row * N_CLS + c] = o[c];
  }
}

// ---------------------------------------------------------------------------
extern "C" void kernel_launch(void* const* d_in, const int* in_sizes, int n_in,
                              void* d_out, int out_size, void* d_ws, size_t ws_size,
                              hipStream_t stream) {
  const float* fs  = (const float*)d_in[0];
  const float* fp  = (const float*)d_in[1];
  const float* gW1 = (const float*)d_in[2];
  const float* gb1 = (const float*)d_in[3];
  const float* gW2 = (const float*)d_in[4];
  const float* gb2 = (const float*)d_in[5];
  const float* gW3 = (const float*)d_in[6];
  const float* gb3 = (const float*)d_in[7];
  const float* eW1 = (const float*)d_in[8];
  const float* eb1 = (const float*)d_in[9];
  const float* eW2 = (const float*)d_in[10];
  const float* eb2 = (const float*)d_in[11];
  const float* eW3 = (const float*)d_in[12];
  const float* eb3 = (const float*)d_in[13];
  float* out = (float*)d_out;                   // [B,10] then [B,8]

  // workspace layout (bytes):
  //   X   : 0          .. 67,108,864   (B*2048 bf16)  -- aliased by H2 later
  //   W1T : 67,108,864 .. 85,983,232   (4608*2048 bf16)
  //   W2T : 85,983,232 .. 87,162,880   (1152*512 bf16)
  //   H1  : 87,162,880 .. 238,157,824  (B*4608 bf16)
  char* ws = (char*)d_ws;
  __hip_bfloat16* X   = (__hip_bfloat16*)ws;
  __hip_bfloat16* H2  = X;   // alias: X dead after gemm1, H2 fits inside
  __hip_bfloat16* W1T = (__hip_bfloat16*)(ws + 67108864);
  __hip_bfloat16* W2T = (__hip_bfloat16*)(ws + 85983232);
  __hip_bfloat16* H1  = (__hip_bfloat16*)(ws + 87162880);

  convert_features_kernel<<<2048, 256, 0, stream>>>(fs, fp, X);
  transpose_convert_kernel<<<dim3(DIN / 32, N1 / 32), dim3(32, 8), 0, stream>>>(
      eW1, gW1, DIN, H1_SZ, N_EXP, W1T);
  transpose_convert_kernel<<<dim3(H1_SZ / 32, N2 / 32), dim3(32, 8), 0, stream>>>(
      eW2, gW2, H1_SZ, H2_SZ, N_EXP, W2T);
  gemm1_kernel8<<<dim3((N1 / 256) * (B_SZ / 256)), 512, 0, stream>>>(
      X, W1T, eb1, gb1, H1);
  gemm2_kernel<<<dim3(1, B_SZ / 128, N_EXP + 1), 256, 0, stream>>>(H1, W2T, eb2, gb2, H2);
  layer3_kernel<<<B_SZ / 32, 256, 0, stream>>>(H2, gW3, gb3, eW3, eb3,
                                               out, out + (size_t)B_SZ * N_CLS);
}